// Round 3
// baseline (205.273 us; speedup 1.0000x reference)
//
#include <hip/hip_runtime.h>
#include <stdint.h>

typedef unsigned long long ull;

#define NA 8400
#define NB 32
#define KTOP 300
#define NC 80
#define CH 9           // 1024*9 = 9216 >= 8400
#define NCOPY 16       // histogram copies (one per wave)
#define HSTRIDE 257    // copies of one bucket land in different banks

// out layout: boxes_yxyx @0 ; in_zone @38400 ; scores @48000 ; classes @57600 ;
//             centers_yx @67200 ; keep @86400 ; total 96000 floats
#define O1 38400
#define O2 48000
#define O3 57600
#define O4 67200
#define O5 86400

// ---------------- A: per-anchor score key (memory-bound, unchanged) ----------------
__global__ __launch_bounds__(256) void score_kernel(const float* __restrict__ pred,
                                                    uint32_t* __restrict__ keys) {
    __shared__ float sP[128 * 85];
    const int blk = blockIdx.x;                       // 2100 blocks * 128 anchors
    const float4* g4 = (const float4*)(pred + (size_t)blk * 128 * 85);
    float4* l4 = (float4*)sP;
    for (int i = threadIdx.x; i < (128 * 85 / 4); i += 256) l4[i] = g4[i];
    __syncthreads();
    const int t = threadIdx.x;
    if (t < 128) {
        const float* p = sP + t * 85;
        float obj = p[4];
        // 4-way interleaved max to break the 80-deep dependence chain (no NaN in inputs)
        float b0 = p[5], b1 = p[6], b2 = p[7], b3 = p[8];
        #pragma unroll
        for (int c = 4; c < NC; c += 4) {
            b0 = fmaxf(b0, p[5 + c]);
            b1 = fmaxf(b1, p[6 + c]);
            b2 = fmaxf(b2, p[7 + c]);
            b3 = fmaxf(b3, p[8 + c]);
        }
        float best = fmaxf(fmaxf(b0, b1), fmaxf(b2, b3));
        float sc = obj * best;
        uint32_t u = (sc >= 0.2f) ? (__float_as_uint(sc) | 0x80000000u) : 0x007FFFFFu;
        keys[(size_t)blk * 128 + t] = u;
    }
}

// ---------------- B: fused per-batch pipeline, keys in registers ----------------
__global__ __launch_bounds__(1024) void batch_kernel(const float* __restrict__ pred,
                                                     const float* __restrict__ zone,
                                                     const uint32_t* __restrict__ keys,
                                                     float* __restrict__ out) {
    #pragma clang fp contract(off)
    __shared__ float sB0[KTOP], sB1[KTOP], sB2[KTOP], sB3[KTOP];
    __shared__ ull sMask[KTOP * 5];
    __shared__ ull sSel[KTOP];
    __shared__ ull sSorted[KTOP];
    __shared__ uint32_t sH[NCOPY * HSTRIDE];
    __shared__ uint32_t sWTot[16];
    __shared__ uint32_t sBc[2];
    __shared__ uint32_t sRank[KTOP];
    __shared__ uint32_t sPar[KTOP];
    __shared__ ull sKeepF[5];
    __shared__ float sZone[16];

    const int b = blockIdx.x;
    const int t = threadIdx.x;
    const int lane = t & 63;
    const int wv = t >> 6;              // 0..15; also the histogram copy id

    // ---- keys straight into registers (9 per thread; pads = 0, never selectable) ----
    uint32_t myk[CH];
    const int beg = t * CH;
    #pragma unroll
    for (int e = 0; e < CH; ++e) {
        int idx = beg + e;
        myk[e] = (idx < NA) ? keys[(size_t)b * NA + idx] : 0u;
    }
    if (t < 16) sZone[t] = zone[t];
    if (t < KTOP) sRank[t] = 0u;        // consumed only after several barriers

    // ---- radix select: exact 300th-largest key; pure-register scans ----
    uint32_t prefix = 0, r = KTOP;
    for (int round = 0; round < 4; ++round) {
        const int shift = 24 - 8 * round;
        for (int i = t; i < NCOPY * HSTRIDE; i += 1024) sH[i] = 0u;
        __syncthreads();
        const uint32_t pmask = (round == 0) ? 0u : (0xFFFFFFFFu << (shift + 8));
        const uint32_t pref = prefix & pmask;
        #pragma unroll
        for (int e = 0; e < CH; ++e) {
            uint32_t k = myk[e];
            if ((k & pmask) == pref)
                atomicAdd(&sH[wv * HSTRIDE + ((k >> shift) & 0xFFu)], 1u);
        }
        __syncthreads();
        if (wv == 0) {                  // single-wave 256-bin suffix scan + pick
            uint32_t v0 = 0, v1 = 0, v2 = 0, v3 = 0;
            #pragma unroll
            for (int c = 0; c < NCOPY; ++c) {
                const uint32_t* hc = &sH[c * HSTRIDE];
                v0 += hc[lane]; v1 += hc[64 + lane];
                v2 += hc[128 + lane]; v3 += hc[192 + lane];
            }
            uint32_t s0 = v0, s1 = v1, s2 = v2, s3 = v3;
            #pragma unroll
            for (int off = 1; off < 64; off <<= 1) {
                uint32_t o0 = __shfl_down(s0, off, 64), o1 = __shfl_down(s1, off, 64);
                uint32_t o2 = __shfl_down(s2, off, 64), o3 = __shfl_down(s3, off, 64);
                if (lane + off < 64) { s0 += o0; s1 += o1; s2 += o2; s3 += o3; }
            }
            uint32_t T1 = __shfl(s1, 0, 64), T2 = __shfl(s2, 0, 64), T3 = __shfl(s3, 0, 64);
            uint32_t S0 = s0 + T1 + T2 + T3;
            uint32_t S1 = s1 + T2 + T3;
            uint32_t S2 = s2 + T3;
            uint32_t S3 = s3;
            if (S0 >= r && S0 - v0 < r) { sBc[0] = prefix | ((uint32_t)lane << shift);         sBc[1] = r - (S0 - v0); }
            if (S1 >= r && S1 - v1 < r) { sBc[0] = prefix | ((uint32_t)(64  + lane) << shift); sBc[1] = r - (S1 - v1); }
            if (S2 >= r && S2 - v2 < r) { sBc[0] = prefix | ((uint32_t)(128 + lane) << shift); sBc[1] = r - (S2 - v2); }
            if (S3 >= r && S3 - v3 < r) { sBc[0] = prefix | ((uint32_t)(192 + lane) << shift); sBc[1] = r - (S3 - v3); }
        }
        __syncthreads();
        prefix = sBc[0]; r = sBc[1];
        // sBc rewritten only after the next round's two barriers. safe.
    }
    const uint32_t kth = prefix;
    const uint32_t rem = r;
    const uint32_t cntgt = KTOP - rem;

    // ---- compaction via packed (gt,eq) prefix scan: no atomics, deterministic ----
    {
        uint32_t gtc = 0, eqc = 0;
        #pragma unroll
        for (int e = 0; e < CH; ++e) {
            uint32_t k = myk[e];
            gtc += (k > kth) ? 1u : 0u;
            eqc += (k == kth) ? 1u : 0u;
        }
        uint32_t pack = (gtc << 16) | eqc;          // totals: gt<=300, eq<=8400 -> no overflow
        uint32_t ps = pack;
        #pragma unroll
        for (int off = 1; off < 64; off <<= 1) {
            uint32_t o = __shfl_up(ps, off, 64);
            if (lane >= off) ps += o;
        }
        if (lane == 63) sWTot[wv] = ps;
        __syncthreads();
        uint32_t excl = ps - pack;                  // exclusive within wave
        #pragma unroll
        for (int w2 = 0; w2 < 16; ++w2) if (w2 < wv) excl += sWTot[w2];
        uint32_t gtoff = excl >> 16;
        uint32_t eqoff = excl & 0xFFFFu;
        #pragma unroll
        for (int e = 0; e < CH; ++e) {
            uint32_t k = myk[e];
            uint32_t idx = (uint32_t)(beg + e);
            if (k > kth) {
                sSel[gtoff++] = ((ull)k << 32) | (ull)(0xFFFFFFFFu - idx);
            } else if (k == kth) {
                if (eqoff < rem)                     // ascending anchor order == top_k tie-break
                    sSel[cntgt + eqoff] = ((ull)k << 32) | (ull)(0xFFFFFFFFu - idx);
                eqoff++;
            }
        }
        __syncthreads();
    }

    // ---- rank sort over 1200 work items (unique 64-bit keys -> rank is a permutation) ----
    for (int p2 = t; p2 < KTOP * 4; p2 += 1024) {
        const int i = p2 >> 2;
        const int q = p2 & 3;
        const ull my = sSel[i];
        const int j0 = q * 75, j1 = j0 + 75;
        uint32_t cnt = 0;
        for (int j = j0; j < j1; ++j)
            cnt += (sSel[j] > my) ? 1u : 0u;
        if (cnt) atomicAdd(&sRank[i], cnt);
    }
    __syncthreads();
    if (t < KTOP) sSorted[sRank[t]] = sSel[t];
    __syncthreads();

    // ---- gather: 2 threads/row, 4 first-max streams each, exact first-max semantics ----
    const size_t bo = (size_t)b * KTOP;
    if (t < 2 * KTOP) {
        const int row = t >> 1;
        const int half = t & 1;
        const uint32_t a = 0xFFFFFFFFu - (uint32_t)sSorted[row];
        const float* p = pred + ((size_t)b * NA + a) * 85;
        const int cbase = half * 40;
        float v0 = p[5 + cbase], v1 = p[6 + cbase], v2 = p[7 + cbase], v3 = p[8 + cbase];
        int   c0 = cbase, c1 = cbase + 1, c2 = cbase + 2, c3 = cbase + 3;
        #pragma unroll
        for (int c = 4; c < 40; c += 4) {
            float w0 = p[5 + cbase + c],     w1 = p[6 + cbase + c];
            float w2 = p[7 + cbase + c],     w3 = p[8 + cbase + c];
            if (w0 > v0) { v0 = w0; c0 = cbase + c; }        // strict >: first-in-stream
            if (w1 > v1) { v1 = w1; c1 = cbase + c + 1; }
            if (w2 > v2) { v2 = w2; c2 = cbase + c + 2; }
            if (w3 > v3) { v3 = w3; c3 = cbase + c + 3; }
        }
        // combine streams with index tie-break -> exact argmax-first
        float bv = v0; int bc = c0;
        if (v1 > bv || (v1 == bv && c1 < bc)) { bv = v1; bc = c1; }
        if (v2 > bv || (v2 == bv && c2 < bc)) { bv = v2; bc = c2; }
        if (v3 > bv || (v3 == bv && c3 < bc)) { bv = v3; bc = c3; }
        // combine halves (partner lane = t^1, same wave since 600 is even)
        float pv = __shfl_xor(bv, 1, 64);
        int   pc = __shfl_xor(bc, 1, 64);
        if (half == 0) {
            if (pv > bv) { bv = pv; bc = pc; }       // partner indices all larger: tie keeps ours
            float x = p[0], y = p[1], w = p[2], h = p[3], obj = p[4];
            float hw = w * 0.5f, hh = h * 0.5f;
            float x1 = x - hw, y1 = y - hh, x2 = x + hw, y2 = y + hh;
            sB0[row] = x1; sB1[row] = y1; sB2[row] = x2; sB3[row] = y2;
            out[(bo + row) * 4 + 0] = y1;
            out[(bo + row) * 4 + 1] = x1;
            out[(bo + row) * 4 + 2] = y2;
            out[(bo + row) * 4 + 3] = x2;
            out[O4 + (bo + row) * 2 + 0] = (y1 + y2) * 0.5f;
            out[O4 + (bo + row) * 2 + 1] = (x1 + x2) * 0.5f;
            out[O2 + bo + row] = fmaxf(obj, bv);
            out[O3 + bo + row] = (float)bc;
        }
    }
    __syncthreads();

    // ---- IoU masks, role-major, uniform-j loop (broadcast LDS reads) ----
    for (int p2 = t; p2 < KTOP * 5; p2 += 1024) {
        const int role = p2 / KTOP;          // lanes mostly share role -> uniform j
        const int i = p2 - role * KTOP;
        const int j0 = role * 64;
        int jmax = j0 + 64; if (jmax > KTOP) jmax = KTOP;
        float x1 = sB0[i], y1 = sB1[i], x2 = sB2[i], y2 = sB3[i];
        float ai = fmaxf(x2 - x1, 0.0f) * fmaxf(y2 - y1, 0.0f);
        ull bits = 0ull;
        for (int j = j0; j < jmax; ++j) {
            float bx1 = sB0[j], by1 = sB1[j], bx2 = sB2[j], by2 = sB3[j];
            float aj = fmaxf(bx2 - bx1, 0.0f) * fmaxf(by2 - by1, 0.0f);
            float iw = fminf(x2, bx2) - fmaxf(x1, bx1); iw = fmaxf(iw, 0.0f);
            float ih = fminf(y2, by2) - fmaxf(y1, by1); ih = fmaxf(ih, 0.0f);
            float inter = iw * ih;
            float den = ai + aj;             // mirror reference op order exactly
            den = den - inter;
            den = den + 1e-9f;
            float iou = inter / den;
            if (j > i && iou > 0.45f) bits |= (1ull << (j - j0));
        }
        sMask[i * 5 + role] = bits;
    }
    __syncthreads();

    // ---- wave 0: greedy NMS.  waves 8-12 (independent): zone parity ----
    if (wv == 0) {
        ull rm[5][5];
        ull kw[5];
        #pragma unroll
        for (int w = 0; w < 5; ++w) {
            int i = w * 64 + lane;
            bool f = (i < KTOP) && (((uint32_t)(sSorted[i] >> 32)) > 0x007FFFFFu);
            kw[w] = __ballot(f);             // keep-init, replicated in every lane
            #pragma unroll
            for (int ww = 0; ww < 5; ++ww)
                rm[w][ww] = (i < KTOP) ? sMask[i * 5 + ww] : 0ull;
        }
        #pragma unroll
        for (int w = 0; w < 5; ++w) {
            ull cur = kw[w];
            while (cur) {
                int ib = __builtin_ctzll(cur);          // accepted box i = w*64+ib
                ull m0 = __shfl(rm[w][0], ib);
                ull m1 = __shfl(rm[w][1], ib);
                ull m2 = __shfl(rm[w][2], ib);
                ull m3 = __shfl(rm[w][3], ib);
                ull m4 = __shfl(rm[w][4], ib);
                kw[0] &= ~m0; kw[1] &= ~m1; kw[2] &= ~m2; kw[3] &= ~m3; kw[4] &= ~m4;
                ull done = (ib == 63) ? 0ull : (~0ull << (ib + 1));
                cur = kw[w] & done;
            }
        }
        if (lane == 0) {
            #pragma unroll
            for (int w = 0; w < 5; ++w) sKeepF[w] = kw[w];
        }
    } else if (t >= 512 && t < 512 + KTOP) {
        const int i = t - 512;
        float cy = (sB1[i] + sB3[i]) * 0.5f;    // bit-identical to centers computation
        float cx = (sB0[i] + sB2[i]) * 0.5f;
        int cnt = 0;
        #pragma unroll
        for (int e = 0; e < 8; ++e) {
            float xi = sZone[2 * e], yi = sZone[2 * e + 1];
            int ep = (e + 7) & 7;               // zr = roll(zone, 1)
            float xj = sZone[2 * ep], yj = sZone[2 * ep + 1];
            bool gyi = yi > cy, gyj = yj > cy;
            if (gyi != gyj) {
                float gx = (xj - xi) * (cy - yi) / (yj - yi) + xi;
                if (gx > cx) cnt++;
            }
        }
        sPar[i] = (uint32_t)(cnt & 1);
    }
    __syncthreads();

    // ---- final keep + in_zone writes ----
    if (t < KTOP) {
        int kp = (int)((sKeepF[t >> 6] >> (t & 63)) & 1ull);
        int inz = (sPar[t] && kp) ? 1 : 0;
        out[O1 + bo + t] = (float)inz;
        out[O5 + bo + t] = (float)kp;
    }
}

extern "C" void kernel_launch(void* const* d_in, const int* in_sizes, int n_in,
                              void* d_out, int out_size, void* d_ws, size_t ws_size,
                              hipStream_t stream) {
    const float* pred = (const float*)d_in[0];   // (32,8400,85) fp32
    const float* zone = (const float*)d_in[1];   // (8,2) fp32
    float* out = (float*)d_out;                  // 96000 fp32
    uint32_t* keys = (uint32_t*)d_ws;            // 32*8400 u32 = 1.075 MB

    score_kernel<<<(NB * NA) / 128, 256, 0, stream>>>(pred, keys);
    batch_kernel<<<NB, 1024, 0, stream>>>(pred, zone, keys, out);
}